// Round 1
// baseline (441.521 us; speedup 1.0000x reference)
//
#include <hip/hip_runtime.h>

#define D_IN_   50937
#define D_LYR_  50425
#define T_      2048
#define NCH     24
#define NBE     16
#define NME     128
#define NOUT    168
#define NPAD    192
#define KROWS   50688        // padded GEMM K: 256 melody + 50432 lyrics (mult of 64)
#define KSPLIT  16
#define TOTSTEP 792          // KROWS/64
#define PARTN   (2048*168)   // 344064

typedef __attribute__((ext_vector_type(8))) short short8;
typedef __attribute__((ext_vector_type(4))) float f32x4;

static __device__ __forceinline__ unsigned short f2bf(float f) {
    unsigned int u = __float_as_uint(f);
    u += 0x7FFF + ((u >> 16) & 1);          // round-to-nearest-even
    return (unsigned short)(u >> 16);
}

// W[d][n] over concatenated heads (padded cols -> 0)
static __device__ __forceinline__ float wsrc(const float* wc, const float* wb,
                                             const float* wm, int d, int n) {
    if (n < NCH)        return wc[d * NCH + n];
    if (n < NCH + NBE)  return wb[d * NBE + (n - NCH)];
    if (n < NOUT)       return wm[d * NME + (n - NCH - NBE)];
    return 0.f;
}

__global__ void k_ctx(const int* genre, const int* tempo, const int* keysig,
                      const float* emb, float* ctx) {
    int d = threadIdx.x;
    int g = genre[0], t = tempo[0], k = keysig[0];
    ctx[d] = emb[g * 256 + d] + emb[(10 + t) * 256 + d] +
             emb[(20 + k) * 256 + d] + emb[34 * 256 + d];
}

// Build folded, transposed, bf16 weights: wbt[n][r], r in [0,KROWS), n in [0,NPAD)
// row r corresponds to d = 256 + r of the original feature axis.
__global__ __launch_bounds__(256) void k_fold(const float* wc, const float* wb,
                                              const float* wm, const float* conv_w,
                                              unsigned short* wbt) {
    __shared__ unsigned short tile[64 * 193];   // [dloc][n], padded row
    float cw0 = conv_w[3], cw1 = conv_w[4], cw2 = conv_w[5];
    int r0 = blockIdx.x * 64;
    int tid = threadIdx.x;
    // phase 1: compute W'[256+r][n] -> LDS (reads coalesced along n)
    for (int i = 0; i < 48; ++i) {
        int idx = tid + i * 256;
        int dl = idx / 192, n = idx % 192;
        int r = r0 + dl;
        float v = 0.f;
        if (r < 50681 && n < NOUT) {
            int d = 256 + r;
            v = cw1 * wsrc(wc, wb, wm, d, n) + cw2 * wsrc(wc, wb, wm, d - 1, n);
            if (d + 1 < D_IN_) v += cw0 * wsrc(wc, wb, wm, d + 1, n);
        }
        tile[dl * 193 + n] = f2bf(v);
    }
    __syncthreads();
    // phase 2: write transposed (coalesced along r), dword-packed
    for (int i = 0; i < 24; ++i) {
        int idx = tid + i * 256;
        int n = idx >> 5, c = idx & 31;
        unsigned int h0 = tile[(c * 2) * 193 + n];
        unsigned int h1 = tile[(c * 2 + 1) * 193 + n];
        *(unsigned int*)(wbt + (long)n * KROWS + r0 + c * 2) = h0 | (h1 << 16);
    }
}

// C[j] = bias + ctx-part + conv_b * colsum  (conv_b==0 path skips the big loop)
__global__ void k_cvec(const float* wc, const float* wb, const float* wm,
                       const float* conv_w, const float* conv_b,
                       const float* bc, const float* bb, const float* bm_,
                       const float* ctx, float* C) {
    int j = threadIdx.x;
    if (j >= NPAD) return;
    float cw0 = conv_w[3], cw1 = conv_w[4], cw2 = conv_w[5];
    float s = 0.f;
    if (j < NOUT) {
        s = (j < NCH) ? bc[j] : (j < NCH + NBE) ? bb[j - NCH] : bm_[j - NCH - NBE];
        for (int d = 0; d < 256; ++d) {
            float wp = cw1 * wsrc(wc, wb, wm, d, j) + cw0 * wsrc(wc, wb, wm, d + 1, j);
            if (d > 0) wp += cw2 * wsrc(wc, wb, wm, d - 1, j);
            s += ctx[d] * wp;
        }
        float cb = conv_b[0];
        if (cb != 0.f) {
            float cs = 0.f;
            for (int d = 0; d < D_IN_; ++d) cs += wsrc(wc, wb, wm, d, j);
            s += cb * cs;
        }
    }
    C[j] = s;
}

// Split-K GEMM: X[2048, KROWS] (fp32 -> bf16 on the fly) @ W'_t -> partial[ks][2048][168]
__global__ __launch_bounds__(512, 4) void k_gemm(const float* mel, const float* lyr,
                                                 const unsigned short* wbt,
                                                 float* partial) {
    __shared__ unsigned short As[64 * 64];    // [row][k], XOR-swizzled, 8 KB
    __shared__ unsigned short Bs[192 * 64];   // [n][k],  XOR-swizzled, 24 KB
    int blk = blockIdx.x;
    int ks = blk & 15, bm = blk >> 4;         // same-ks neighbors share XCD L2 for B
    int tid = threadIdx.x, lane = tid & 63, wv = tid >> 6;
    int wm = wv & 1, wn = wv >> 1;            // 2 M-groups x 4 N-groups of waves
    f32x4 zero4 = {0.f, 0.f, 0.f, 0.f};
    f32x4 acc[2][3];
    for (int mi = 0; mi < 2; ++mi)
        for (int ni = 0; ni < 3; ++ni) acc[mi][ni] = zero4;

    int start = ks * 49 + (ks < 8 ? ks : 8);
    int cnt = 49 + (ks < 8 ? 1 : 0);

    for (int s = start; s < start + cnt; ++s) {
        int r0 = s * 64;
        // ---- stage A: 64 rows x 64 k, one fp32 per lane, coalesced 256B/row ----
        for (int i = 0; i < 8; ++i) {
            int row = wv * 8 + i;
            int t = bm * 64 + row;
            int r = r0 + lane;
            float v;
            if (r < 256) v = mel[t * 256 + r];
            else {
                int c = r - 256;
                v = (c < D_LYR_) ? lyr[(long)t * D_LYR_ + c] : 0.f;
            }
            int byte = row * 128 + (((lane * 2)) ^ ((row & 7) << 4));
            *(unsigned short*)((char*)As + byte) = f2bf(v);
        }
        // ---- stage B: 192 n x 64 k bf16, dword loads (L2/L3-resident) ----
        const unsigned int* w32 = (const unsigned int*)wbt;
        for (int i = 0; i < 12; ++i) {
            int idx = tid + i * 512;
            int n = idx >> 5, c = idx & 31;
            unsigned int pk = w32[(long)n * (KROWS / 2) + (r0 >> 1) + c];
            int byte = n * 128 + (((c * 4)) ^ ((n & 7) << 4));
            *(unsigned int*)((char*)Bs + byte) = pk;
        }
        __syncthreads();
        // ---- MFMA: 2 k-halves x (2m x 3n) 16x16x32 ----
        for (int kk = 0; kk < 2; ++kk) {
            short8 a[2], b[3];
            for (int mi = 0; mi < 2; ++mi) {
                int row = wm * 32 + mi * 16 + (lane & 15);
                int byte = row * 128 +
                           (((kk * 64) + ((lane >> 4) * 16)) ^ ((row & 7) << 4));
                a[mi] = *(const short8*)((const char*)As + byte);
            }
            for (int ni = 0; ni < 3; ++ni) {
                int n = wn * 48 + ni * 16 + (lane & 15);
                int byte = n * 128 +
                           (((kk * 64) + ((lane >> 4) * 16)) ^ ((n & 7) << 4));
                b[ni] = *(const short8*)((const char*)Bs + byte);
            }
            for (int mi = 0; mi < 2; ++mi)
                for (int ni = 0; ni < 3; ++ni)
                    acc[mi][ni] = __builtin_amdgcn_mfma_f32_16x16x32_bf16(
                        a[mi], b[ni], acc[mi][ni], 0, 0, 0);
        }
        __syncthreads();
    }
    // ---- epilogue: deterministic partial store ----
    float* pbase = partial + (long)ks * PARTN;
    for (int mi = 0; mi < 2; ++mi) {
        int rbase = bm * 64 + wm * 32 + mi * 16 + ((lane >> 4) * 4);
        for (int ni = 0; ni < 3; ++ni) {
            int col = wn * 48 + ni * 16 + (lane & 15);
            if (col < NOUT) {
                for (int q = 0; q < 4; ++q)
                    pbase[(long)(rbase + q) * NOUT + col] = acc[mi][ni][q];
            }
        }
    }
}

__global__ void k_reduce(const float* partial, const float* C, float* out) {
    int idx = blockIdx.x * 256 + threadIdx.x;
    if (idx >= PARTN) return;
    int j = idx % NOUT;
    float s = C[j];
    for (int ks = 0; ks < KSPLIT; ++ks) s += partial[(long)ks * PARTN + idx];
    out[idx] = s;
}

extern "C" void kernel_launch(void* const* d_in, const int* in_sizes, int n_in,
                              void* d_out, int out_size, void* d_ws, size_t ws_size,
                              hipStream_t stream) {
    const int*   genre   = (const int*)d_in[0];
    const int*   tempo   = (const int*)d_in[1];
    const int*   keysig  = (const int*)d_in[2];
    const float* mel     = (const float*)d_in[4];
    const float* lyr     = (const float*)d_in[5];
    const float* emb     = (const float*)d_in[6];
    const float* conv_w  = (const float*)d_in[7];
    const float* conv_b  = (const float*)d_in[8];
    const float* w_chord = (const float*)d_in[9];
    const float* b_chord = (const float*)d_in[10];
    const float* w_beat  = (const float*)d_in[11];
    const float* b_beat  = (const float*)d_in[12];
    const float* w_mel   = (const float*)d_in[13];
    const float* b_mel   = (const float*)d_in[14];

    char* ws = (char*)d_ws;
    unsigned short* wbt = (unsigned short*)ws;              // 192*50688*2 = 19,464,192 B
    float* ctx     = (float*)(ws + 19464192);               // 1 KB
    float* Cvec    = (float*)(ws + 19464192 + 1024);        // 1 KB
    float* partial = (float*)(ws + 19466240);               // 16*344064*4 = 22,020,096 B
    float* out     = (float*)d_out;

    hipLaunchKernelGGL(k_ctx, dim3(1), dim3(256), 0, stream,
                       genre, tempo, keysig, emb, ctx);
    hipLaunchKernelGGL(k_fold, dim3(TOTSTEP), dim3(256), 0, stream,
                       w_chord, w_beat, w_mel, conv_w, wbt);
    hipLaunchKernelGGL(k_cvec, dim3(1), dim3(192), 0, stream,
                       w_chord, w_beat, w_mel, conv_w, conv_b,
                       b_chord, b_beat, b_mel, ctx, Cvec);
    hipLaunchKernelGGL(k_gemm, dim3(512), dim3(512), 0, stream,
                       mel, lyr, wbt, partial);
    hipLaunchKernelGGL(k_reduce, dim3(1344), dim3(256), 0, stream,
                       partial, Cvec, out);
}

// Round 2
// 180.851 us; speedup vs baseline: 2.4413x; 2.4413x over previous
//
#include <hip/hip_runtime.h>

#define D_IN_   50937
#define D_LYR_  50425
#define T_      2048
#define NCH     24
#define NBE     16
#define NME     128
#define NOUT    168
#define NPAD    192
#define KROWS   50688        // padded GEMM K: 256 melody + 50432 lyrics (mult of 64)
#define KSPLIT  16
#define TOTSTEP 792          // KROWS/64
#define PARTN   (2048*168)   // 344064

typedef __attribute__((ext_vector_type(8))) short short8;
typedef __attribute__((ext_vector_type(4))) float f32x4;
typedef float f32x4u __attribute__((ext_vector_type(4), aligned(4)));
typedef __attribute__((ext_vector_type(2))) unsigned int u32x2;

static __device__ __forceinline__ unsigned short f2bf(float f) {
    unsigned int u = __float_as_uint(f);
    u += 0x7FFF + ((u >> 16) & 1);          // round-to-nearest-even
    return (unsigned short)(u >> 16);
}
static __device__ __forceinline__ unsigned int pack2(float x, float y) {
    return (unsigned int)f2bf(x) | ((unsigned int)f2bf(y) << 16);
}

// scalar W[d][n] over concatenated heads
static __device__ __forceinline__ float wsrc(const float* wc, const float* wb,
                                             const float* wm, int d, int n) {
    if (n < NCH)        return wc[d * NCH + n];
    if (n < NCH + NBE)  return wb[d * NBE + (n - NCH)];
    if (n < NOUT)       return wm[(long)d * NME + (n - NCH - NBE)];
    return 0.f;
}
// quad W[d][n0..n0+3]; head boundaries (24,40,168) are 4-aligned so quads never straddle
static __device__ __forceinline__ f32x4 wsrc4(const float* wc, const float* wb,
                                              const float* wm, int d, int nq) {
    int n0 = nq * 4;
    if (n0 < 24)  return *(const f32x4*)(wc + d * 24 + n0);
    if (n0 < 40)  return *(const f32x4*)(wb + d * 16 + (n0 - 24));
    if (n0 < 168) return *(const f32x4*)(wm + (long)d * 128 + (n0 - 40));
    f32x4 z = {0.f, 0.f, 0.f, 0.f};
    return z;
}

__global__ void k_ctx(const int* genre, const int* tempo, const int* keysig,
                      const float* emb, float* ctx) {
    int d = threadIdx.x;
    int g = genre[0], t = tempo[0], k = keysig[0];
    ctx[d] = emb[g * 256 + d] + emb[(10 + t) * 256 + d] +
             emb[(20 + k) * 256 + d] + emb[34 * 256 + d];
}

// folded, transposed, bf16 weights: wbt[n][r], r = d-256
__global__ __launch_bounds__(256) void k_fold(const float* wc, const float* wb,
                                              const float* wm_, const float* conv_w,
                                              unsigned short* wbt) {
    __shared__ unsigned short tile[64 * 196];   // [dloc][n], pad 196 (8B-aligned rows)
    float cw0 = conv_w[3], cw1 = conv_w[4], cw2 = conv_w[5];
    int r0 = blockIdx.x * 64;
    int tid = threadIdx.x;
    // phase 1: quads of folded W' -> LDS
    for (int i = 0; i < 12; ++i) {
        int idx = tid + i * 256;                // 64 rows x 48 quads
        int dl = idx / 48, nq = idx % 48;
        int r = r0 + dl;
        f32x4 v = {0.f, 0.f, 0.f, 0.f};
        if (r < 50681) {
            int d = 256 + r;
            f32x4 w0 = wsrc4(wc, wb, wm_, d, nq);
            f32x4 wn1 = wsrc4(wc, wb, wm_, d - 1, nq);
            v = cw1 * w0 + cw2 * wn1;
            if (d + 1 < D_IN_) v += cw0 * wsrc4(wc, wb, wm_, d + 1, nq);
        }
        u32x2 p; p.x = pack2(v.x, v.y); p.y = pack2(v.z, v.w);
        *(u32x2*)&tile[dl * 196 + nq * 4] = p;
    }
    __syncthreads();
    // phase 2: transposed 16B stores along r
    for (int i = 0; i < 6; ++i) {
        int idx = tid + i * 256;                // 192 n x 8 chunks
        int n = idx >> 3, ch = idx & 7;
        short8 o;
        for (int j = 0; j < 8; ++j) o[j] = (short)tile[(ch * 8 + j) * 196 + n];
        *(short8*)(wbt + (long)n * KROWS + r0 + ch * 8) = o;
    }
}

// C[j] = bias + ctx @ W'[0:256, j] (+ conv_b * colsum, generally zero)
__global__ void k_cvec(const float* wc, const float* wb, const float* wm_,
                       const float* conv_w, const float* conv_b,
                       const float* bc, const float* bb, const float* bm_,
                       const float* ctx, float* C) {
    int j = blockIdx.x;          // 0..167
    int lane = threadIdx.x;      // 64
    float cw0 = conv_w[3], cw1 = conv_w[4], cw2 = conv_w[5];
    float s = 0.f;
    for (int d = lane; d < 256; d += 64) {
        float wp = cw1 * wsrc(wc, wb, wm_, d, j) + cw0 * wsrc(wc, wb, wm_, d + 1, j);
        if (d > 0) wp += cw2 * wsrc(wc, wb, wm_, d - 1, j);
        s += ctx[d] * wp;
    }
    float cb = conv_b[0];
    if (cb != 0.f) {
        float cs = 0.f;
        for (int d = lane; d < D_IN_; d += 64) cs += wsrc(wc, wb, wm_, d, j);
        s += cb * cs;
    }
    for (int off = 32; off; off >>= 1) s += __shfl_down(s, off);
    if (lane == 0) {
        float b = (j < NCH) ? bc[j] : (j < NCH + NBE) ? bb[j - NCH] : bm_[j - NCH - NBE];
        C[j] = s + b;
    }
}

static __device__ __forceinline__ f32x4 loadArow(const float* mel, const float* lyr,
                                                 int t, int r) {
    if (r < 256) return *(const f32x4u*)(mel + t * 256 + r);
    int c = r - 256;
    if (c + 3 < D_LYR_) return *(const f32x4u*)(lyr + (long)t * D_LYR_ + c);
    f32x4 v;
    for (int j = 0; j < 4; ++j)
        v[j] = (c + j < D_LYR_) ? lyr[(long)t * D_LYR_ + c + j] : 0.f;
    return v;
}

// Split-K GEMM, double-buffered 2-phase pipeline.
__global__ __launch_bounds__(512, 4) void k_gemm(const float* mel, const float* lyr,
                                                 const unsigned short* wbt,
                                                 float* partial) {
    __shared__ unsigned short As[2 * 64 * 64];    // 2 x 8 KB, XOR-swizzled
    __shared__ unsigned short Bs[2 * 192 * 64];   // 2 x 24 KB, XOR-swizzled
    int blk = blockIdx.x;
    int ks = ((blk & 7) << 1) | ((blk >> 3) & 1);  // XCD x holds ks {2x,2x+1} B-slices
    int bm = blk >> 4;
    int tid = threadIdx.x, lane = tid & 63, wv = tid >> 6;
    int wm = wv & 1, wn = wv >> 1;                 // 2 M-groups x 4 N-groups
    f32x4 zero4 = {0.f, 0.f, 0.f, 0.f};
    f32x4 acc[2][3];
    for (int mi = 0; mi < 2; ++mi)
        for (int ni = 0; ni < 3; ++ni) acc[mi][ni] = zero4;

    int start = ks * 49 + (ks < 8 ? ks : 8);
    int cnt = 49 + (ks < 8 ? 1 : 0);

    int f4 = tid & 15, rowl = tid >> 4;            // A-load coords (2 rows/thread)
    int bn = tid >> 3, bch = tid & 7;              // B-load coords (3 n-chunks/thread)

    // ---- prologue: stage tile `start` into buffer 0 ----
    {
        int r0 = start * 64;
        f32x4 a0 = loadArow(mel, lyr, bm * 64 + rowl, r0 + f4 * 4);
        f32x4 a1 = loadArow(mel, lyr, bm * 64 + rowl + 32, r0 + f4 * 4);
        short8 brg[3];
        for (int i = 0; i < 3; ++i) {
            int n = bn + i * 64;
            brg[i] = *(const short8*)(wbt + (long)n * KROWS + r0 + bch * 8);
        }
        int rb0 = rowl, rb1 = rowl + 32;
        u32x2 p0; p0.x = pack2(a0.x, a0.y); p0.y = pack2(a0.z, a0.w);
        u32x2 p1; p1.x = pack2(a1.x, a1.y); p1.y = pack2(a1.z, a1.w);
        *(u32x2*)((char*)As + rb0 * 128 + ((f4 * 8) ^ ((rb0 & 7) << 4))) = p0;
        *(u32x2*)((char*)As + rb1 * 128 + ((f4 * 8) ^ ((rb1 & 7) << 4))) = p1;
        for (int i = 0; i < 3; ++i) {
            int n = bn + i * 64;
            *(short8*)((char*)Bs + n * 128 + ((bch * 16) ^ ((n & 7) << 4))) = brg[i];
        }
    }
    __syncthreads();

    for (int t = 0; t < cnt; ++t) {
        const char* Ac = (const char*)As + (t & 1) * 8192;
        const char* Bc = (const char*)Bs + (t & 1) * 24576;
        char* An = (char*)As + ((t & 1) ^ 1) * 8192;
        char* Bn = (char*)Bs + ((t & 1) ^ 1) * 24576;
        bool pf = (t + 1 < cnt);
        f32x4 a0, a1; short8 brg[3];
        if (pf) {   // issue next-tile loads BEFORE compute (stay in flight under MFMA)
            int r0 = (start + t + 1) * 64;
            a0 = loadArow(mel, lyr, bm * 64 + rowl, r0 + f4 * 4);
            a1 = loadArow(mel, lyr, bm * 64 + rowl + 32, r0 + f4 * 4);
            for (int i = 0; i < 3; ++i) {
                int n = bn + i * 64;
                brg[i] = *(const short8*)(wbt + (long)n * KROWS + r0 + bch * 8);
            }
        }
        // ---- compute current tile ----
        for (int kk = 0; kk < 2; ++kk) {
            short8 af[2], bfr[3];
            for (int mi = 0; mi < 2; ++mi) {
                int row = wm * 32 + mi * 16 + (lane & 15);
                int byte = row * 128 +
                           (((kk * 64) + ((lane >> 4) * 16)) ^ ((row & 7) << 4));
                af[mi] = *(const short8*)(Ac + byte);
            }
            for (int ni = 0; ni < 3; ++ni) {
                int n = wn * 48 + ni * 16 + (lane & 15);
                int byte = n * 128 +
                           (((kk * 64) + ((lane >> 4) * 16)) ^ ((n & 7) << 4));
                bfr[ni] = *(const short8*)(Bc + byte);
            }
            for (int mi = 0; mi < 2; ++mi)
                for (int ni = 0; ni < 3; ++ni)
                    acc[mi][ni] = __builtin_amdgcn_mfma_f32_16x16x32_bf16(
                        af[mi], bfr[ni], acc[mi][ni], 0, 0, 0);
        }
        if (pf) {   // write prefetched tile into the other buffer
            int rb0 = rowl, rb1 = rowl + 32;
            u32x2 p0; p0.x = pack2(a0.x, a0.y); p0.y = pack2(a0.z, a0.w);
            u32x2 p1; p1.x = pack2(a1.x, a1.y); p1.y = pack2(a1.z, a1.w);
            *(u32x2*)(An + rb0 * 128 + ((f4 * 8) ^ ((rb0 & 7) << 4))) = p0;
            *(u32x2*)(An + rb1 * 128 + ((f4 * 8) ^ ((rb1 & 7) << 4))) = p1;
            for (int i = 0; i < 3; ++i) {
                int n = bn + i * 64;
                *(short8*)(Bn + n * 128 + ((bch * 16) ^ ((n & 7) << 4))) = brg[i];
            }
        }
        __syncthreads();
    }

    // ---- epilogue: deterministic partial store ----
    float* pbase = partial + (long)ks * PARTN;
    for (int mi = 0; mi < 2; ++mi) {
        int rbase = bm * 64 + wm * 32 + mi * 16 + ((lane >> 4) * 4);
        for (int ni = 0; ni < 3; ++ni) {
            int col = wn * 48 + ni * 16 + (lane & 15);
            if (col < NOUT) {
                for (int q = 0; q < 4; ++q)
                    pbase[(long)(rbase + q) * NOUT + col] = acc[mi][ni][q];
            }
        }
    }
}

__global__ void k_reduce(const float* partial, const float* C, float* out) {
    int idx = blockIdx.x * 256 + threadIdx.x;
    if (idx >= PARTN) return;
    int j = idx % NOUT;
    float s = C[j];
    for (int ks = 0; ks < KSPLIT; ++ks) s += partial[(long)ks * PARTN + idx];
    out[idx] = s;
}

extern "C" void kernel_launch(void* const* d_in, const int* in_sizes, int n_in,
                              void* d_out, int out_size, void* d_ws, size_t ws_size,
                              hipStream_t stream) {
    const int*   genre   = (const int*)d_in[0];
    const int*   tempo   = (const int*)d_in[1];
    const int*   keysig  = (const int*)d_in[2];
    const float* mel     = (const float*)d_in[4];
    const float* lyr     = (const float*)d_in[5];
    const float* emb     = (const float*)d_in[6];
    const float* conv_w  = (const float*)d_in[7];
    const float* conv_b  = (const float*)d_in[8];
    const float* w_chord = (const float*)d_in[9];
    const float* b_chord = (const float*)d_in[10];
    const float* w_beat  = (const float*)d_in[11];
    const float* b_beat  = (const float*)d_in[12];
    const float* w_mel   = (const float*)d_in[13];
    const float* b_mel   = (const float*)d_in[14];

    char* ws = (char*)d_ws;
    unsigned short* wbt = (unsigned short*)ws;              // 192*50688*2 = 19,464,192 B
    float* ctx     = (float*)(ws + 19464192);               // 1 KB
    float* Cvec    = (float*)(ws + 19464192 + 1024);        // 1 KB
    float* partial = (float*)(ws + 19466240);               // 16*344064*4 = 22,020,096 B
    float* out     = (float*)d_out;

    hipLaunchKernelGGL(k_ctx, dim3(1), dim3(256), 0, stream,
                       genre, tempo, keysig, emb, ctx);
    hipLaunchKernelGGL(k_fold, dim3(TOTSTEP), dim3(256), 0, stream,
                       w_chord, w_beat, w_mel, conv_w, wbt);
    hipLaunchKernelGGL(k_cvec, dim3(168), dim3(64), 0, stream,
                       w_chord, w_beat, w_mel, conv_w, conv_b,
                       b_chord, b_beat, b_mel, ctx, Cvec);
    hipLaunchKernelGGL(k_gemm, dim3(512), dim3(512), 0, stream,
                       mel, lyr, wbt, partial);
    hipLaunchKernelGGL(k_reduce, dim3(1344), dim3(256), 0, stream,
                       partial, Cvec, out);
}